// Round 1
// baseline (1022.817 us; speedup 1.0000x reference)
//
#include <hip/hip_runtime.h>

#define NFEAT 256
#define NHID 64
#define NHEAD 8
#define HID1 512   // NHEAD*NHID
#define NOUT 128

// ---------------- CSR build ----------------
__global__ void k_hist(const int* __restrict__ dstA, int E, int n, int* __restrict__ deg) {
    int i = blockIdx.x * blockDim.x + threadIdx.x;
    if (i >= E + n) return;
    int d = (i < E) ? dstA[i] : (i - E);   // self-loop edges appended
    atomicAdd(&deg[d], 1);
}

__global__ __launch_bounds__(1024) void k_scan(const int* __restrict__ deg, int* __restrict__ indptr, int n) {
    __shared__ int part[1024];
    int t = threadIdx.x;
    int chunk = (n + 1023) >> 10;
    int b = t * chunk;
    int e = min(b + chunk, n);
    int s = 0;
    for (int i = b; i < e; ++i) s += deg[i];
    part[t] = s;
    __syncthreads();
    for (int off = 1; off < 1024; off <<= 1) {
        int v = (t >= off) ? part[t - off] : 0;
        __syncthreads();
        part[t] += v;
        __syncthreads();
    }
    int run = (t == 0) ? 0 : part[t - 1];
    for (int i = b; i < e; ++i) { indptr[i] = run; run += deg[i]; }
    if (t == 1023) indptr[n] = part[1023];
}

__global__ void k_fill(const int* __restrict__ srcA, const int* __restrict__ dstA, int E, int n,
                       const int* __restrict__ indptr, int* __restrict__ cnt, int* __restrict__ csr_src) {
    int i = blockIdx.x * blockDim.x + threadIdx.x;
    if (i >= E + n) return;
    int s, d;
    if (i < E) { s = srcA[i]; d = dstA[i]; } else { s = i - E; d = s; }
    int pos = indptr[d] + atomicAdd(&cnt[d], 1);
    csr_src[pos] = s;
}

// ---------------- fp32 tiled GEMM: C[M,N] = A[M,K] @ B[K,N] ----------------
// requires N % 64 == 0, K % 16 == 0 (true here: N in {512,128}, K in {256,512})
__global__ __launch_bounds__(256) void k_gemm(const float* __restrict__ A, const float* __restrict__ B,
                                              float* __restrict__ C, int M, int N, int K) {
    __shared__ float As[16][64 + 1];
    __shared__ float Bs[16][64 + 4];
    int m0 = blockIdx.y * 64;
    int n0 = blockIdx.x * 64;
    int t = threadIdx.x;
    int tr = (t / 16) * 4;
    int tc = (t % 16) * 4;
    float acc[4][4] = {};
    for (int k0 = 0; k0 < K; k0 += 16) {
        for (int idx = t; idx < 64 * 16; idx += 256) {
            int r = idx / 16, kk = idx % 16;
            int gr = m0 + r;
            As[kk][r] = (gr < M) ? A[(size_t)gr * K + k0 + kk] : 0.f;
        }
        for (int idx = t; idx < 16 * 64; idx += 256) {
            int kk = idx / 64, c = idx % 64;
            Bs[kk][c] = B[(size_t)(k0 + kk) * N + n0 + c];
        }
        __syncthreads();
        #pragma unroll
        for (int kk = 0; kk < 16; ++kk) {
            float a[4], b[4];
            #pragma unroll
            for (int i = 0; i < 4; ++i) a[i] = As[kk][tr + i];
            #pragma unroll
            for (int j = 0; j < 4; ++j) b[j] = Bs[kk][tc + j];
            #pragma unroll
            for (int i = 0; i < 4; ++i)
                #pragma unroll
                for (int j = 0; j < 4; ++j)
                    acc[i][j] += a[i] * b[j];
        }
        __syncthreads();
    }
    for (int i = 0; i < 4; ++i) {
        int gr = m0 + tr + i;
        if (gr >= M) break;
        #pragma unroll
        for (int j = 0; j < 4; ++j)
            C[(size_t)gr * N + n0 + tc + j] = acc[i][j];
    }
}

// ---------------- layer 1 attention logits: el/er [N,8] ----------------
__global__ __launch_bounds__(256) void k_elr1(const float* __restrict__ feat, const float* __restrict__ al,
                                              const float* __restrict__ ar, float* __restrict__ el,
                                              float* __restrict__ er, int n) {
    int node = blockIdx.x;
    if (node >= n) return;
    int t = threadIdx.x;
    int w = t >> 6;                 // wave -> heads w and w+4
    const float* f = feat + (size_t)node * HID1;
    float p0 = f[t] * al[t];
    float q0 = f[t] * ar[t];
    float p1 = f[t + 256] * al[t + 256];
    float q1 = f[t + 256] * ar[t + 256];
    for (int o = 32; o > 0; o >>= 1) {
        p0 += __shfl_down(p0, o);
        q0 += __shfl_down(q0, o);
        p1 += __shfl_down(p1, o);
        q1 += __shfl_down(q1, o);
    }
    if ((t & 63) == 0) {
        el[node * NHEAD + w] = p0;
        er[node * NHEAD + w] = q0;
        el[node * NHEAD + w + 4] = p1;
        er[node * NHEAD + w + 4] = q1;
    }
}

// ---------------- layer 1 aggregate + bias + ELU -> h1 [N,512] ----------------
// one wave per (node, head); lane = d. No max-shift: logits bounded ~|26|, exp safe in fp32.
__global__ __launch_bounds__(256) void k_agg1(const float* __restrict__ feat, const float* __restrict__ el,
                                              const float* __restrict__ er, const float* __restrict__ b1,
                                              const int* __restrict__ indptr, const int* __restrict__ csr_src,
                                              float* __restrict__ hout, int n) {
    int wid = blockIdx.x * 4 + (threadIdx.x >> 6);
    int lane = threadIdx.x & 63;
    int node = wid >> 3;
    int h = wid & 7;
    if (node >= n) return;
    int e0 = indptr[node], e1 = indptr[node + 1];
    float erv = er[node * NHEAD + h];
    float acc = 0.f, den = 0.f;
    for (int e = e0; e < e1; ++e) {
        int s = csr_src[e];
        float x = el[s * NHEAD + h] + erv;
        x = (x > 0.f) ? x : 0.2f * x;
        float wgt = __expf(x);
        den += wgt;
        acc += wgt * feat[(size_t)s * HID1 + h * NHID + lane];
    }
    float v = acc / den + b1[h * NHID + lane];
    v = (v > 0.f) ? v : (__expf(v) - 1.f);   // ELU
    hout[(size_t)node * HID1 + h * NHID + lane] = v;
}

// ---------------- layer 2 logits: el2/er2 [N] ----------------
__global__ __launch_bounds__(256) void k_elr2(const float* __restrict__ feat2, const float* __restrict__ al2,
                                              const float* __restrict__ ar2, float* __restrict__ el2,
                                              float* __restrict__ er2, int n) {
    int wid = blockIdx.x * 4 + (threadIdx.x >> 6);
    int lane = threadIdx.x & 63;
    if (wid >= n) return;
    const float* f = feat2 + (size_t)wid * NOUT;
    float p = f[lane] * al2[lane] + f[lane + 64] * al2[lane + 64];
    float q = f[lane] * ar2[lane] + f[lane + 64] * ar2[lane + 64];
    for (int o = 32; o > 0; o >>= 1) { p += __shfl_down(p, o); q += __shfl_down(q, o); }
    if (lane == 0) { el2[wid] = p; er2[wid] = q; }
}

// ---------------- layer 2 aggregate + bias -> out [N,128] ----------------
__global__ __launch_bounds__(256) void k_agg2(const float* __restrict__ feat2, const float* __restrict__ el2,
                                              const float* __restrict__ er2, const float* __restrict__ b2,
                                              const int* __restrict__ indptr, const int* __restrict__ csr_src,
                                              float* __restrict__ out, int n) {
    int wid = blockIdx.x * 4 + (threadIdx.x >> 6);
    int lane = threadIdx.x & 63;
    if (wid >= n) return;
    int e0 = indptr[wid], e1 = indptr[wid + 1];
    float erv = er2[wid];
    float a0 = 0.f, a1 = 0.f, den = 0.f;
    for (int e = e0; e < e1; ++e) {
        int s = csr_src[e];
        float x = el2[s] + erv;
        x = (x > 0.f) ? x : 0.2f * x;
        float wgt = __expf(x);
        den += wgt;
        a0 += wgt * feat2[(size_t)s * NOUT + lane];
        a1 += wgt * feat2[(size_t)s * NOUT + 64 + lane];
    }
    out[(size_t)wid * NOUT + lane] = a0 / den + b2[lane];
    out[(size_t)wid * NOUT + 64 + lane] = a1 / den + b2[64 + lane];
}

extern "C" void kernel_launch(void* const* d_in, const int* in_sizes, int n_in,
                              void* d_out, int out_size, void* d_ws, size_t ws_size,
                              hipStream_t stream) {
    const float* x   = (const float*)d_in[0];
    const int*   ei  = (const int*)d_in[1];
    const float* W1  = (const float*)d_in[2];
    const float* al1 = (const float*)d_in[3];
    const float* ar1 = (const float*)d_in[4];
    const float* b1  = (const float*)d_in[5];
    const float* W2  = (const float*)d_in[6];
    const float* al2 = (const float*)d_in[7];
    const float* ar2 = (const float*)d_in[8];
    const float* b2  = (const float*)d_in[9];

    const int n  = in_sizes[0] / NFEAT;   // 50000
    const int E  = in_sizes[1] / 2;       // 400000
    const int ET = E + n;                 // + self loops
    const int* srcA = ei;
    const int* dstA = ei + E;

    // workspace layout (~236 MB)
    char* ws = (char*)d_ws;
    size_t off = 0;
    auto alloc = [&](size_t bytes) -> void* {
        void* p = ws + off;
        off += (bytes + 255) & ~(size_t)255;
        return p;
    };
    float* feat1  = (float*)alloc((size_t)n * HID1 * 4);
    float* h1     = (float*)alloc((size_t)n * HID1 * 4);
    float* feat2  = (float*)alloc((size_t)n * NOUT * 4);
    float* el1    = (float*)alloc((size_t)n * NHEAD * 4);
    float* er1    = (float*)alloc((size_t)n * NHEAD * 4);
    float* el2    = (float*)alloc((size_t)n * 4);
    float* er2    = (float*)alloc((size_t)n * 4);
    int*   indptr = (int*)alloc((size_t)(n + 1) * 4);
    int*   deg    = (int*)alloc((size_t)n * 4);       // deg and cnt adjacent:
    int*   cnt    = (int*)alloc((size_t)n * 4);       // zeroed with one memset each
    int*   csr    = (int*)alloc((size_t)ET * 4);

    hipMemsetAsync(deg, 0, (size_t)n * 4, stream);
    hipMemsetAsync(cnt, 0, (size_t)n * 4, stream);

    // CSR build
    k_hist<<<(ET + 255) / 256, 256, 0, stream>>>(dstA, E, n, deg);
    k_scan<<<1, 1024, 0, stream>>>(deg, indptr, n);
    k_fill<<<(ET + 255) / 256, 256, 0, stream>>>(srcA, dstA, E, n, indptr, cnt, csr);

    // layer 1
    k_gemm<<<dim3(HID1 / 64, (n + 63) / 64), 256, 0, stream>>>(x, W1, feat1, n, HID1, NFEAT);
    k_elr1<<<n, 256, 0, stream>>>(feat1, al1, ar1, el1, er1, n);
    k_agg1<<<(n * NHEAD) / 4, 256, 0, stream>>>(feat1, el1, er1, b1, indptr, csr, h1, n);

    // layer 2
    k_gemm<<<dim3(NOUT / 64, (n + 63) / 64), 256, 0, stream>>>(h1, W2, feat2, n, NOUT, HID1);
    k_elr2<<<(n + 3) / 4, 256, 0, stream>>>(feat2, al2, ar2, el2, er2, n);
    k_agg2<<<(n + 3) / 4, 256, 0, stream>>>(feat2, el2, er2, b2, indptr, csr, (float*)d_out, n);
}

// Round 2
// 536.017 us; speedup vs baseline: 1.9082x; 1.9082x over previous
//
#include <hip/hip_runtime.h>

#define NFEAT 256
#define NHID 64
#define NHEAD 8
#define HID1 512   // NHEAD*NHID
#define NOUT 128

typedef unsigned short ushort_t;
typedef unsigned int uint_t;
typedef __attribute__((ext_vector_type(8))) short short8;
typedef __attribute__((ext_vector_type(4))) float floatx4;

static __device__ __forceinline__ float bf2f(uint_t s) {
    return __uint_as_float(s << 16);
}
static __device__ __forceinline__ ushort_t f2bf(float f) {
    uint_t u = __float_as_uint(f);
    u += 0x7FFF + ((u >> 16) & 1);   // RNE; inputs finite
    return (ushort_t)(u >> 16);
}

// ---------------- CSR build ----------------
__global__ void k_hist(const int* __restrict__ dstA, int E, int n, int* __restrict__ deg) {
    int i = blockIdx.x * blockDim.x + threadIdx.x;
    if (i >= E + n) return;
    int d = (i < E) ? dstA[i] : (i - E);
    atomicAdd(&deg[d], 1);
}

__global__ __launch_bounds__(1024) void k_scan(const int* __restrict__ deg, int* __restrict__ indptr, int n) {
    __shared__ int part[1024];
    int t = threadIdx.x;
    int chunk = (n + 1023) >> 10;
    int b = t * chunk;
    int e = min(b + chunk, n);
    int s = 0;
    for (int i = b; i < e; ++i) s += deg[i];
    part[t] = s;
    __syncthreads();
    for (int off = 1; off < 1024; off <<= 1) {
        int v = (t >= off) ? part[t - off] : 0;
        __syncthreads();
        part[t] += v;
        __syncthreads();
    }
    int run = (t == 0) ? 0 : part[t - 1];
    for (int i = b; i < e; ++i) { indptr[i] = run; run += deg[i]; }
    if (t == 1023) indptr[n] = part[1023];
}

__global__ void k_fill(const int* __restrict__ srcA, const int* __restrict__ dstA, int E, int n,
                       const int* __restrict__ indptr, int* __restrict__ cnt, int* __restrict__ csr_src) {
    int i = blockIdx.x * blockDim.x + threadIdx.x;
    if (i >= E + n) return;
    int s, d;
    if (i < E) { s = srcA[i]; d = dstA[i]; } else { s = i - E; d = s; }
    int pos = indptr[d] + atomicAdd(&cnt[d], 1);
    csr_src[pos] = s;
}

// ---------------- bf16 MFMA GEMM: C[M,N](bf16) = A[M,K] @ B[K,N](fp32) ----------------
// A is fp32 (ABF16=false) or bf16 row-major (ABF16=true). N%64==0, K%32==0.
// Tile 64x64, BK=32, 256 threads (4 waves), wave w owns rows [w*16,w*16+16).
template <bool ABF16>
__global__ __launch_bounds__(256) void k_gemm_mfma(const void* __restrict__ Aptr,
                                                   const float* __restrict__ B,
                                                   ushort_t* __restrict__ C,
                                                   int M, int N, int K) {
    __shared__ __align__(16) ushort_t As[64 * 40];   // [row][k], pad 32->40
    __shared__ __align__(16) ushort_t Bs[64 * 40];   // [col][k], pad 32->40
    int t = threadIdx.x;
    int m0 = blockIdx.y * 64, n0 = blockIdx.x * 64;
    int w = t >> 6, lane = t & 63;
    int l16 = lane & 15, quad = lane >> 4;

    floatx4 acc[4] = {{0,0,0,0},{0,0,0,0},{0,0,0,0},{0,0,0,0}};

    int ar = t >> 2, ak0 = (t & 3) * 8;     // A staging: 4 thr/row, 8 k each
    int bk = t >> 3, bc0 = (t & 7) * 8;     // B staging: 8 thr/k-row, 8 n each

    for (int k0 = 0; k0 < K; k0 += 32) {
        // stage A tile (convert to bf16 if needed)
        int gr = m0 + ar;
        short8 aval = {0,0,0,0,0,0,0,0};
        if (gr < M) {
            if (ABF16) {
                const ushort_t* Ab = (const ushort_t*)Aptr;
                aval = *(const short8*)(Ab + (size_t)gr * K + k0 + ak0);
            } else {
                const float* Af = (const float*)Aptr;
                const floatx4* p = (const floatx4*)(Af + (size_t)gr * K + k0 + ak0);
                floatx4 f0 = p[0], f1 = p[1];
                #pragma unroll
                for (int i = 0; i < 4; ++i) {
                    aval[i]     = (short)f2bf(f0[i]);
                    aval[i + 4] = (short)f2bf(f1[i]);
                }
            }
        }
        *(short8*)(&As[ar * 40 + ak0]) = aval;

        // stage B tile transposed: Bs[col][k]
        {
            const floatx4* p = (const floatx4*)(B + (size_t)(k0 + bk) * N + n0 + bc0);
            floatx4 f0 = p[0], f1 = p[1];
            #pragma unroll
            for (int i = 0; i < 4; ++i) {
                Bs[(bc0 + i) * 40 + bk]     = f2bf(f0[i]);
                Bs[(bc0 + 4 + i) * 40 + bk] = f2bf(f1[i]);
            }
        }
        __syncthreads();

        short8 a = *(const short8*)(&As[(w * 16 + l16) * 40 + quad * 8]);
        #pragma unroll
        for (int ct = 0; ct < 4; ++ct) {
            short8 b = *(const short8*)(&Bs[(ct * 16 + l16) * 40 + quad * 8]);
            acc[ct] = __builtin_amdgcn_mfma_f32_16x16x32_bf16(a, b, acc[ct], 0, 0, 0);
        }
        __syncthreads();
    }

    // epilogue: D[row=quad*4+r][col=l16] per 16x16 tile
    #pragma unroll
    for (int ct = 0; ct < 4; ++ct) {
        #pragma unroll
        for (int r = 0; r < 4; ++r) {
            int row = m0 + w * 16 + quad * 4 + r;
            if (row < M)
                C[(size_t)row * N + n0 + ct * 16 + l16] = f2bf(acc[ct][r]);
        }
    }
}

// ---------------- layer 1 logits from bf16 feat ----------------
__global__ __launch_bounds__(256) void k_elr1(const uint_t* __restrict__ fb, const float* __restrict__ al,
                                              const float* __restrict__ ar, float* __restrict__ el,
                                              float* __restrict__ er, int n) {
    int node = blockIdx.x;
    int t = threadIdx.x;
    uint_t u = fb[(size_t)node * 256 + t];       // elems 2t, 2t+1 (head h = t>>5)
    float lo = bf2f(u & 0xFFFF), hi = bf2f(u >> 16);
    float p = lo * al[2 * t] + hi * al[2 * t + 1];
    float q = lo * ar[2 * t] + hi * ar[2 * t + 1];
    for (int o = 16; o > 0; o >>= 1) {
        p += __shfl_down(p, o, 32);
        q += __shfl_down(q, o, 32);
    }
    if ((t & 31) == 0) {
        int h = t >> 5;
        el[node * NHEAD + h] = p;
        er[node * NHEAD + h] = q;
    }
}

// ---------------- layer 1 aggregate (fused heads) + bias + ELU -> h1 bf16 ----------------
// one 256-thread block per node; thread t covers elems 2t,2t+1 (head t>>5).
__global__ __launch_bounds__(256) void k_agg1(const uint_t* __restrict__ fb, const float* __restrict__ el,
                                              const float* __restrict__ er, const float* __restrict__ b1,
                                              const int* __restrict__ indptr, const int* __restrict__ csr_src,
                                              uint_t* __restrict__ h1b, int n) {
    int node = blockIdx.x;
    int t = threadIdx.x;
    int h = t >> 5;
    float erv = er[node * NHEAD + h];
    int e0 = indptr[node], e1 = indptr[node + 1];
    float a0 = 0.f, a1 = 0.f, den = 0.f;
    for (int e = e0; e < e1; ++e) {
        int s = csr_src[e];
        float x = el[s * NHEAD + h] + erv;
        x = (x > 0.f) ? x : 0.2f * x;
        float w = __expf(x);
        den += w;
        uint_t u = fb[(size_t)s * 256 + t];
        a0 += w * bf2f(u & 0xFFFF);
        a1 += w * bf2f(u >> 16);
    }
    float inv = 1.f / den;
    float v0 = a0 * inv + b1[2 * t];
    float v1 = a1 * inv + b1[2 * t + 1];
    v0 = (v0 > 0.f) ? v0 : (__expf(v0) - 1.f);
    v1 = (v1 > 0.f) ? v1 : (__expf(v1) - 1.f);
    h1b[(size_t)node * 256 + t] = (uint_t)f2bf(v0) | ((uint_t)f2bf(v1) << 16);
}

// ---------------- layer 2 logits ----------------
__global__ __launch_bounds__(256) void k_elr2(const uint_t* __restrict__ fb2, const float* __restrict__ al2,
                                              const float* __restrict__ ar2, float* __restrict__ el2,
                                              float* __restrict__ er2, int n) {
    int wid = blockIdx.x * 4 + (threadIdx.x >> 6);
    int lane = threadIdx.x & 63;
    if (wid >= n) return;
    uint_t u = fb2[(size_t)wid * 64 + lane];     // elems 2*lane, 2*lane+1
    float lo = bf2f(u & 0xFFFF), hi = bf2f(u >> 16);
    float p = lo * al2[2 * lane] + hi * al2[2 * lane + 1];
    float q = lo * ar2[2 * lane] + hi * ar2[2 * lane + 1];
    for (int o = 32; o > 0; o >>= 1) { p += __shfl_down(p, o); q += __shfl_down(q, o); }
    if (lane == 0) { el2[wid] = p; er2[wid] = q; }
}

// ---------------- layer 2 aggregate + bias -> out fp32 ----------------
__global__ __launch_bounds__(256) void k_agg2(const uint_t* __restrict__ fb2, const float* __restrict__ el2,
                                              const float* __restrict__ er2, const float* __restrict__ b2,
                                              const int* __restrict__ indptr, const int* __restrict__ csr_src,
                                              float* __restrict__ out, int n) {
    int wid = blockIdx.x * 4 + (threadIdx.x >> 6);
    int lane = threadIdx.x & 63;
    if (wid >= n) return;
    float erv = er2[wid];
    int e0 = indptr[wid], e1 = indptr[wid + 1];
    float a0 = 0.f, a1 = 0.f, den = 0.f;
    for (int e = e0; e < e1; ++e) {
        int s = csr_src[e];
        float x = el2[s] + erv;
        x = (x > 0.f) ? x : 0.2f * x;
        float w = __expf(x);
        den += w;
        uint_t u = fb2[(size_t)s * 64 + lane];
        a0 += w * bf2f(u & 0xFFFF);
        a1 += w * bf2f(u >> 16);
    }
    float inv = 1.f / den;
    float2 o;
    o.x = a0 * inv + b2[2 * lane];
    o.y = a1 * inv + b2[2 * lane + 1];
    ((float2*)out)[(size_t)wid * 64 + lane] = o;
}

extern "C" void kernel_launch(void* const* d_in, const int* in_sizes, int n_in,
                              void* d_out, int out_size, void* d_ws, size_t ws_size,
                              hipStream_t stream) {
    const float* x   = (const float*)d_in[0];
    const int*   ei  = (const int*)d_in[1];
    const float* W1  = (const float*)d_in[2];
    const float* al1 = (const float*)d_in[3];
    const float* ar1 = (const float*)d_in[4];
    const float* b1  = (const float*)d_in[5];
    const float* W2  = (const float*)d_in[6];
    const float* al2 = (const float*)d_in[7];
    const float* ar2 = (const float*)d_in[8];
    const float* b2  = (const float*)d_in[9];

    const int n  = in_sizes[0] / NFEAT;   // 50000
    const int E  = in_sizes[1] / 2;       // 400000
    const int ET = E + n;
    const int* srcA = ei;
    const int* dstA = ei + E;

    char* ws = (char*)d_ws;
    size_t off = 0;
    auto alloc = [&](size_t bytes) -> void* {
        void* p = ws + off;
        off += (bytes + 255) & ~(size_t)255;
        return p;
    };
    ushort_t* feat1b = (ushort_t*)alloc((size_t)n * HID1 * 2);   // 51.2 MB
    ushort_t* h1b    = (ushort_t*)alloc((size_t)n * HID1 * 2);   // 51.2 MB
    ushort_t* feat2b = (ushort_t*)alloc((size_t)n * NOUT * 2);   // 12.8 MB
    float* el1 = (float*)alloc((size_t)n * NHEAD * 4);
    float* er1 = (float*)alloc((size_t)n * NHEAD * 4);
    float* el2 = (float*)alloc((size_t)n * 4);
    float* er2 = (float*)alloc((size_t)n * 4);
    int* indptr = (int*)alloc((size_t)(n + 1) * 4);
    int* deg    = (int*)alloc((size_t)n * 4);
    int* cnt    = (int*)alloc((size_t)n * 4);
    int* csr    = (int*)alloc((size_t)ET * 4);

    hipMemsetAsync(deg, 0, (size_t)n * 4, stream);
    hipMemsetAsync(cnt, 0, (size_t)n * 4, stream);

    // CSR build
    k_hist<<<(ET + 255) / 256, 256, 0, stream>>>(dstA, E, n, deg);
    k_scan<<<1, 1024, 0, stream>>>(deg, indptr, n);
    k_fill<<<(ET + 255) / 256, 256, 0, stream>>>(srcA, dstA, E, n, indptr, cnt, csr);

    // layer 1: GEMM (fp32 A -> bf16 C), logits, fused-head aggregate
    k_gemm_mfma<false><<<dim3(HID1 / 64, (n + 63) / 64), 256, 0, stream>>>(x, W1, feat1b, n, HID1, NFEAT);
    k_elr1<<<n, 256, 0, stream>>>((const uint_t*)feat1b, al1, ar1, el1, er1, n);
    k_agg1<<<n, 256, 0, stream>>>((const uint_t*)feat1b, el1, er1, b1, indptr, csr, (uint_t*)h1b, n);

    // layer 2
    k_gemm_mfma<true><<<dim3(NOUT / 64, (n + 63) / 64), 256, 0, stream>>>(h1b, W2, feat2b, n, NOUT, HID1);
    k_elr2<<<(n + 3) / 4, 256, 0, stream>>>((const uint_t*)feat2b, al2, ar2, el2, er2, n);
    k_agg2<<<(n + 3) / 4, 256, 0, stream>>>((const uint_t*)feat2b, el2, er2, b2, indptr, csr, (float*)d_out, n);
}

// Round 3
// 451.618 us; speedup vs baseline: 2.2648x; 1.1869x over previous
//
#include <hip/hip_runtime.h>

#define NFEAT 256
#define NHID 64
#define NHEAD 8
#define HID1 512   // NHEAD*NHID
#define NOUT 128

typedef unsigned short ushort_t;
typedef unsigned int uint_t;
typedef __attribute__((ext_vector_type(8))) short short8;
typedef __attribute__((ext_vector_type(4))) float floatx4;
typedef __attribute__((ext_vector_type(4))) ushort_t ushort4_t;

static __device__ __forceinline__ float bf2f(uint_t s) {
    return __uint_as_float(s << 16);
}
static __device__ __forceinline__ ushort_t f2bf(float f) {
    uint_t u = __float_as_uint(f);
    u += 0x7FFF + ((u >> 16) & 1);   // RNE; inputs finite
    return (ushort_t)(u >> 16);
}

// ---------------- CSR build ----------------
__global__ void k_hist(const int* __restrict__ dstA, int E, int n, int* __restrict__ deg) {
    int i = blockIdx.x * blockDim.x + threadIdx.x;
    if (i >= E + n) return;
    int d = (i < E) ? dstA[i] : (i - E);
    atomicAdd(&deg[d], 1);
}

__global__ __launch_bounds__(1024) void k_scan(const int* __restrict__ deg, int* __restrict__ indptr, int n) {
    __shared__ int part[1024];
    int t = threadIdx.x;
    int chunk = (n + 1023) >> 10;
    int b = t * chunk;
    int e = min(b + chunk, n);
    int s = 0;
    for (int i = b; i < e; ++i) s += deg[i];
    part[t] = s;
    __syncthreads();
    for (int off = 1; off < 1024; off <<= 1) {
        int v = (t >= off) ? part[t - off] : 0;
        __syncthreads();
        part[t] += v;
        __syncthreads();
    }
    int run = (t == 0) ? 0 : part[t - 1];
    for (int i = b; i < e; ++i) { indptr[i] = run; run += deg[i]; }
    if (t == 1023) indptr[n] = part[1023];
}

__global__ void k_fill(const int* __restrict__ srcA, const int* __restrict__ dstA, int E, int n,
                       const int* __restrict__ indptr, int* __restrict__ cnt, int* __restrict__ csr_src) {
    int i = blockIdx.x * blockDim.x + threadIdx.x;
    if (i >= E + n) return;
    int s, d;
    if (i < E) { s = srcA[i]; d = dstA[i]; } else { s = i - E; d = s; }
    int pos = indptr[d] + atomicAdd(&cnt[d], 1);
    csr_src[pos] = s;
}

// ---------------- prep: fp32 -> bf16 cast (4 elems/thread) ----------------
__global__ void k_cast(const float* __restrict__ x, ushort_t* __restrict__ xb, int total4) {
    int i = blockIdx.x * blockDim.x + threadIdx.x;
    if (i >= total4) return;
    floatx4 f = ((const floatx4*)x)[i];
    ushort4_t o;
    #pragma unroll
    for (int j = 0; j < 4; ++j) o[j] = f2bf(f[j]);
    ((ushort4_t*)xb)[i] = o;
}

// ---------------- prep: W[K][N] fp32 -> Wt[N][K] bf16 ----------------
__global__ void k_prepw(const float* __restrict__ W, ushort_t* __restrict__ Wt, int K, int N) {
    int i = blockIdx.x * blockDim.x + threadIdx.x;   // i = n*K + k
    if (i >= K * N) return;
    int nn = i / K, kk = i % K;
    Wt[i] = f2bf(W[(size_t)kk * N + nn]);
}

// ---------------- bf16 MFMA GEMM, m97 structure ----------------
// C[M,N] = A[M,K] @ Bt[N,K]^T, all bf16. 128x128 tile, BK=32, 256 threads.
// global_load_lds width=16; LDS layout row-major [128][32], NO padding.
__global__ __launch_bounds__(256) void k_gemm128(const ushort_t* __restrict__ A,
                                                 const ushort_t* __restrict__ Bt,
                                                 ushort_t* __restrict__ C,
                                                 int M, int N, int K) {
    __shared__ __align__(16) ushort_t As[128 * 32];
    __shared__ __align__(16) ushort_t Bs[128 * 32];
    const int t = threadIdx.x;
    const int w = t >> 6, lane = t & 63;
    const int l16 = lane & 15, quad = lane >> 4;
    const int m0 = blockIdx.y * 128, n0 = blockIdx.x * 128;
    const int r0 = (w >> 1) * 64;   // wave's local row base
    const int c0 = (w & 1) * 64;    // wave's local col base

    floatx4 acc[4][4] = {};

    // staging: idx = j*256 + t; covers row idx>>2, k-part (idx&3)*8 (16B)
    const int srow[2] = { (0 * 256 + t) >> 2, (1 * 256 + t) >> 2 };
    const int skp = (t & 3) * 8;
    const int wbase0 = (0 * 256 + (t & ~63)) * 8;   // LDS elem offset, wave-uniform
    const int wbase1 = (1 * 256 + (t & ~63)) * 8;

    for (int k0 = 0; k0 < K; k0 += 32) {
        {
            int gr0 = m0 + srow[0]; if (gr0 >= M) gr0 = M - 1;
            int gr1 = m0 + srow[1]; if (gr1 >= M) gr1 = M - 1;
            const ushort_t* gpa0 = A + (size_t)gr0 * K + k0 + skp;
            const ushort_t* gpa1 = A + (size_t)gr1 * K + k0 + skp;
            const ushort_t* gpb0 = Bt + (size_t)(n0 + srow[0]) * K + k0 + skp;
            const ushort_t* gpb1 = Bt + (size_t)(n0 + srow[1]) * K + k0 + skp;
            __builtin_amdgcn_global_load_lds((const __attribute__((address_space(1))) void*)gpa0,
                (__attribute__((address_space(3))) void*)(As + wbase0), 16, 0, 0);
            __builtin_amdgcn_global_load_lds((const __attribute__((address_space(1))) void*)gpa1,
                (__attribute__((address_space(3))) void*)(As + wbase1), 16, 0, 0);
            __builtin_amdgcn_global_load_lds((const __attribute__((address_space(1))) void*)gpb0,
                (__attribute__((address_space(3))) void*)(Bs + wbase0), 16, 0, 0);
            __builtin_amdgcn_global_load_lds((const __attribute__((address_space(1))) void*)gpb1,
                (__attribute__((address_space(3))) void*)(Bs + wbase1), 16, 0, 0);
        }
        __syncthreads();

        short8 af[4], bf[4];
        #pragma unroll
        for (int i = 0; i < 4; ++i)
            af[i] = *(const short8*)(As + (r0 + i * 16 + l16) * 32 + quad * 8);
        #pragma unroll
        for (int j = 0; j < 4; ++j)
            bf[j] = *(const short8*)(Bs + (c0 + j * 16 + l16) * 32 + quad * 8);
        #pragma unroll
        for (int i = 0; i < 4; ++i)
            #pragma unroll
            for (int j = 0; j < 4; ++j)
                acc[i][j] = __builtin_amdgcn_mfma_f32_16x16x32_bf16(af[i], bf[j], acc[i][j], 0, 0, 0);
        __syncthreads();
    }

    // epilogue: D row = quad*4 + r, col = l16 within each 16x16 tile
    #pragma unroll
    for (int i = 0; i < 4; ++i) {
        #pragma unroll
        for (int r = 0; r < 4; ++r) {
            int row = m0 + r0 + i * 16 + quad * 4 + r;
            if (row < M) {
                #pragma unroll
                for (int j = 0; j < 4; ++j)
                    C[(size_t)row * N + n0 + c0 + j * 16 + l16] = f2bf(acc[i][j][r]);
            }
        }
    }
}

// ---------------- layer 1 logits from bf16 feat ----------------
__global__ __launch_bounds__(256) void k_elr1(const uint_t* __restrict__ fb, const float* __restrict__ al,
                                              const float* __restrict__ ar, float* __restrict__ el,
                                              float* __restrict__ er, int n) {
    int node = blockIdx.x;
    int t = threadIdx.x;
    uint_t u = fb[(size_t)node * 256 + t];       // elems 2t, 2t+1 (head h = t>>5)
    float lo = bf2f(u & 0xFFFF), hi = bf2f(u >> 16);
    float p = lo * al[2 * t] + hi * al[2 * t + 1];
    float q = lo * ar[2 * t] + hi * ar[2 * t + 1];
    for (int o = 16; o > 0; o >>= 1) {
        p += __shfl_down(p, o, 32);
        q += __shfl_down(q, o, 32);
    }
    if ((t & 31) == 0) {
        int h = t >> 5;
        el[node * NHEAD + h] = p;
        er[node * NHEAD + h] = q;
    }
}

// ---------------- layer 1 aggregate (fused heads, 2-way unroll) + bias + ELU ----------------
__global__ __launch_bounds__(256) void k_agg1(const uint_t* __restrict__ fb, const float* __restrict__ el,
                                              const float* __restrict__ er, const float* __restrict__ b1,
                                              const int* __restrict__ indptr, const int* __restrict__ csr_src,
                                              uint_t* __restrict__ h1b, int n) {
    int node = blockIdx.x;
    int t = threadIdx.x;
    int h = t >> 5;
    float erv = er[node * NHEAD + h];
    int e0 = indptr[node], e1 = indptr[node + 1];
    float a0 = 0.f, a1 = 0.f, den = 0.f;
    int e = e0;
    for (; e + 1 < e1; e += 2) {
        int s0 = csr_src[e], s1 = csr_src[e + 1];
        float x0 = el[s0 * NHEAD + h] + erv;
        float x1 = el[s1 * NHEAD + h] + erv;
        uint_t u0 = fb[(size_t)s0 * 256 + t];
        uint_t u1 = fb[(size_t)s1 * 256 + t];
        x0 = (x0 > 0.f) ? x0 : 0.2f * x0;
        x1 = (x1 > 0.f) ? x1 : 0.2f * x1;
        float w0 = __expf(x0), w1 = __expf(x1);
        den += w0 + w1;
        a0 += w0 * bf2f(u0 & 0xFFFF) + w1 * bf2f(u1 & 0xFFFF);
        a1 += w0 * bf2f(u0 >> 16) + w1 * bf2f(u1 >> 16);
    }
    if (e < e1) {
        int s = csr_src[e];
        float x = el[s * NHEAD + h] + erv;
        x = (x > 0.f) ? x : 0.2f * x;
        float w = __expf(x);
        den += w;
        uint_t u = fb[(size_t)s * 256 + t];
        a0 += w * bf2f(u & 0xFFFF);
        a1 += w * bf2f(u >> 16);
    }
    float inv = 1.f / den;
    float v0 = a0 * inv + b1[2 * t];
    float v1 = a1 * inv + b1[2 * t + 1];
    v0 = (v0 > 0.f) ? v0 : (__expf(v0) - 1.f);
    v1 = (v1 > 0.f) ? v1 : (__expf(v1) - 1.f);
    h1b[(size_t)node * 256 + t] = (uint_t)f2bf(v0) | ((uint_t)f2bf(v1) << 16);
}

// ---------------- layer 2 logits ----------------
__global__ __launch_bounds__(256) void k_elr2(const uint_t* __restrict__ fb2, const float* __restrict__ al2,
                                              const float* __restrict__ ar2, float* __restrict__ el2,
                                              float* __restrict__ er2, int n) {
    int wid = blockIdx.x * 4 + (threadIdx.x >> 6);
    int lane = threadIdx.x & 63;
    if (wid >= n) return;
    uint_t u = fb2[(size_t)wid * 64 + lane];
    float lo = bf2f(u & 0xFFFF), hi = bf2f(u >> 16);
    float p = lo * al2[2 * lane] + hi * al2[2 * lane + 1];
    float q = lo * ar2[2 * lane] + hi * ar2[2 * lane + 1];
    for (int o = 32; o > 0; o >>= 1) { p += __shfl_down(p, o); q += __shfl_down(q, o); }
    if (lane == 0) { el2[wid] = p; er2[wid] = q; }
}

// ---------------- layer 2 aggregate (2-way unroll) + bias -> out fp32 ----------------
__global__ __launch_bounds__(256) void k_agg2(const uint_t* __restrict__ fb2, const float* __restrict__ el2,
                                              const float* __restrict__ er2, const float* __restrict__ b2,
                                              const int* __restrict__ indptr, const int* __restrict__ csr_src,
                                              float* __restrict__ out, int n) {
    int wid = blockIdx.x * 4 + (threadIdx.x >> 6);
    int lane = threadIdx.x & 63;
    if (wid >= n) return;
    float erv = er2[wid];
    int e0 = indptr[wid], e1 = indptr[wid + 1];
    float a0 = 0.f, a1 = 0.f, den = 0.f;
    int e = e0;
    for (; e + 1 < e1; e += 2) {
        int s0 = csr_src[e], s1 = csr_src[e + 1];
        float x0 = el2[s0] + erv;
        float x1 = el2[s1] + erv;
        uint_t u0 = fb2[(size_t)s0 * 64 + lane];
        uint_t u1 = fb2[(size_t)s1 * 64 + lane];
        x0 = (x0 > 0.f) ? x0 : 0.2f * x0;
        x1 = (x1 > 0.f) ? x1 : 0.2f * x1;
        float w0 = __expf(x0), w1 = __expf(x1);
        den += w0 + w1;
        a0 += w0 * bf2f(u0 & 0xFFFF) + w1 * bf2f(u1 & 0xFFFF);
        a1 += w0 * bf2f(u0 >> 16) + w1 * bf2f(u1 >> 16);
    }
    if (e < e1) {
        int s = csr_src[e];
        float x = el2[s] + erv;
        x = (x > 0.f) ? x : 0.2f * x;
        float w = __expf(x);
        den += w;
        uint_t u = fb2[(size_t)s * 64 + lane];
        a0 += w * bf2f(u & 0xFFFF);
        a1 += w * bf2f(u >> 16);
    }
    float inv = 1.f / den;
    float2 o;
    o.x = a0 * inv + b2[2 * lane];
    o.y = a1 * inv + b2[2 * lane + 1];
    ((float2*)out)[(size_t)wid * 64 + lane] = o;
}

extern "C" void kernel_launch(void* const* d_in, const int* in_sizes, int n_in,
                              void* d_out, int out_size, void* d_ws, size_t ws_size,
                              hipStream_t stream) {
    const float* x   = (const float*)d_in[0];
    const int*   ei  = (const int*)d_in[1];
    const float* W1  = (const float*)d_in[2];
    const float* al1 = (const float*)d_in[3];
    const float* ar1 = (const float*)d_in[4];
    const float* b1  = (const float*)d_in[5];
    const float* W2  = (const float*)d_in[6];
    const float* al2 = (const float*)d_in[7];
    const float* ar2 = (const float*)d_in[8];
    const float* b2  = (const float*)d_in[9];

    const int n  = in_sizes[0] / NFEAT;   // 50000
    const int E  = in_sizes[1] / 2;       // 400000
    const int ET = E + n;
    const int* srcA = ei;
    const int* dstA = ei + E;

    char* ws = (char*)d_ws;
    size_t off = 0;
    auto alloc = [&](size_t bytes) -> void* {
        void* p = ws + off;
        off += (bytes + 255) & ~(size_t)255;
        return p;
    };
    ushort_t* xb     = (ushort_t*)alloc((size_t)n * NFEAT * 2);  // 25.6 MB
    ushort_t* feat1b = (ushort_t*)alloc((size_t)n * HID1 * 2);   // 51.2 MB
    ushort_t* h1b    = (ushort_t*)alloc((size_t)n * HID1 * 2);   // 51.2 MB
    ushort_t* feat2b = (ushort_t*)alloc((size_t)n * NOUT * 2);   // 12.8 MB
    ushort_t* W1t    = (ushort_t*)alloc((size_t)NFEAT * HID1 * 2);
    ushort_t* W2t    = (ushort_t*)alloc((size_t)HID1 * NOUT * 2);
    float* el1 = (float*)alloc((size_t)n * NHEAD * 4);
    float* er1 = (float*)alloc((size_t)n * NHEAD * 4);
    float* el2 = (float*)alloc((size_t)n * 4);
    float* er2 = (float*)alloc((size_t)n * 4);
    int* indptr = (int*)alloc((size_t)(n + 1) * 4);
    int* deg    = (int*)alloc((size_t)n * 4);
    int* cnt    = (int*)alloc((size_t)n * 4);
    int* csr    = (int*)alloc((size_t)ET * 4);

    hipMemsetAsync(deg, 0, (size_t)n * 4, stream);
    hipMemsetAsync(cnt, 0, (size_t)n * 4, stream);

    // CSR build
    k_hist<<<(ET + 255) / 256, 256, 0, stream>>>(dstA, E, n, deg);
    k_scan<<<1, 1024, 0, stream>>>(deg, indptr, n);
    k_fill<<<(ET + 255) / 256, 256, 0, stream>>>(srcA, dstA, E, n, indptr, cnt, csr);

    // prep: cast x, transpose+cast weights
    k_cast<<<((n * NFEAT / 4) + 255) / 256, 256, 0, stream>>>(x, xb, n * NFEAT / 4);
    k_prepw<<<(NFEAT * HID1 + 255) / 256, 256, 0, stream>>>(W1, W1t, NFEAT, HID1);
    k_prepw<<<(HID1 * NOUT + 255) / 256, 256, 0, stream>>>(W2, W2t, HID1, NOUT);

    // layer 1
    k_gemm128<<<dim3(HID1 / 128, (n + 127) / 128), 256, 0, stream>>>(xb, W1t, feat1b, n, HID1, NFEAT);
    k_elr1<<<n, 256, 0, stream>>>((const uint_t*)feat1b, al1, ar1, el1, er1, n);
    k_agg1<<<n, 256, 0, stream>>>((const uint_t*)feat1b, el1, er1, b1, indptr, csr, (uint_t*)h1b, n);

    // layer 2
    k_gemm128<<<dim3(NOUT / 128, (n + 127) / 128), 256, 0, stream>>>(h1b, W2t, feat2b, n, NOUT, HID1);
    k_elr2<<<(n + 3) / 4, 256, 0, stream>>>((const uint_t*)feat2b, al2, ar2, el2, er2, n);
    k_agg2<<<(n + 3) / 4, 256, 0, stream>>>((const uint_t*)feat2b, el2, er2, b2, indptr, csr, (float*)d_out, n);
}